// Round 4
// baseline (449.522 us; speedup 1.0000x reference)
//
#include <hip/hip_runtime.h>
#include <hip/hip_bf16.h>
#include <stdint.h>

#define B_    256
#define T_    512
#define N_    256
#define START_ 254
#define STOP_  255
#define GCOLS 16
#define NDM   16          // merged denominator blocks (fwd+bwd in one block)
#define LOG2E 1.4426950408889634f
#define LN2   0.6931471805599453f

// d_ws float layout: [0,65536) alphaF, [65536,131072) betaB, [131072,131328) CF,
// [131328,131584) CB, [131584,131840) numerator partials
#define WSB_OFF 65536
#define WCF_OFF 131072
#define WCB_OFF 131328
#define WNUM_OFF 131584

typedef __attribute__((ext_vector_type(4))) float floatx4;
typedef __attribute__((ext_vector_type(4))) unsigned int uintx4;
typedef __attribute__((ext_vector_type(8))) int v8i;

template<bool X> struct BC { static constexpr bool value = X; };

__device__ __forceinline__ void lds_barrier() {
    asm volatile("s_waitcnt lgkmcnt(0)\n\ts_barrier" ::: "memory");
}
__device__ __forceinline__ float fmax3(float a, float b, float c) {
    return fmaxf(fmaxf(a, b), c);   // clang fuses to v_max3_f32
}
__device__ __forceinline__ uint32_t umax32(uint32_t a, uint32_t b) {
    return a > b ? a : b;           // v_max_u32
}
// VALU-pipe butterfly (keeps reduce off the DS unit): after swap,
// {a, b} = {x[l], x[l^16]} (resp ^32).
__device__ __forceinline__ float pmax16(float x) {
    float a = x, b = x;
    asm("v_permlane16_swap_b32 %0, %1" : "+v"(a), "+v"(b));
    return fmaxf(a, b);
}
__device__ __forceinline__ float pmax32(float x) {
    float a = x, b = x;
    asm("v_permlane32_swap_b32 %0, %1" : "+v"(a), "+v"(b));
    return fmaxf(a, b);
}
__device__ __forceinline__ float psum32(float x) {
    float a = x, b = x;
    asm("v_permlane32_swap_b32 %0, %1" : "+v"(a), "+v"(b));
    return a + b;
}

__device__ __forceinline__ int pk_fp8x4(float a, float b, float c, float d) {  // e4m3
    int r = __builtin_amdgcn_cvt_pk_fp8_f32(a, b, 0, false);
    return __builtin_amdgcn_cvt_pk_fp8_f32(c, d, r, true);
}
__device__ __forceinline__ int pk_bf8x4(float a, float b, float c, float d) {  // e5m2
    int r = __builtin_amdgcn_cvt_pk_bf8_f32(a, b, 0, false);
    return __builtin_amdgcn_cvt_pk_bf8_f32(c, d, r, true);
}

// V layout (per buffer, 4096 B): element (k, col b), k = state index:
//   c=k>>7, qk=(k>>5)&3, j=k&31, r=j>>4, j'=j&15
//   addr = ((c*2+r)<<10) + (qk<<8) + (b<<4) + j'
// Read (lane l=q*16+b, chunk c): two b128 at (2c)*1024+16l and (2c+1)*1024+16l
// -> contiguous 1KB per wave per page, zero conflicts.
// mbuf: per-column max partials packed as truncated-bf16 u16[8] (positive
// floats compare as integers; truncation keeps the exponent; rs uses only
// the exponent -> bit-identical to an f32 max reduce).
struct DenomShared {
    alignas(16) char  VF[2][4096];
    alignas(16) char  VB[2][4096];
    alignas(16) unsigned short mbufF[GCOLS * 8];
    alignas(16) unsigned short mbufB[GCOLS * 8];
    alignas(16) float sbufF[GCOLS * 20];   // sum partials (mask-dead path only)
    alignas(16) float sbufB[GCOLS * 20];
    int flag;
};

// MERGED fwd+bwd: 16 blocks, each owns 16 batch columns and runs BOTH chains
// interleaved with ONE barrier per pair of steps. While the F stream sits in
// its V-read/MFMA latency, the B stream's VALU/DS work fills the gap (R1-R3
// showed ~300cy/step of lockstep barrier/latency slack with one stream).
// 512 threads = 8 waves; wave w owns rows [32w,32w+32) as 2 M-tiles (per dir).
// Lane l: q=l>>4, b=l&15. A = E (e4m3, fwd) and E^T (bwd), persistent in
// VGPRs. B-operand = V (e5m2) in LDS, dbuffered per dir.
// Emission pipeline per dir (depth-2): load raw @ s+2, convert @ s+1,
// consume @ s. Rescale rs is a pure power of two -> exact.
__device__ __forceinline__ void denom_both(
    DenomShared& sh, const float* __restrict__ inputs,
    const float* __restrict__ trans, const int* __restrict__ mask,
    float* __restrict__ ws, int blkLocal)
{
    const int tid = threadIdx.x;
    const int w = tid >> 6;
    const int l = tid & 63;
    const int q = l >> 4;
    const int b = l & 15;
    const int bg = blkLocal * GCOLS + b;
    const int j0 = 32 * w + 4 * q;          // + 16*mt
    const int scl = 0x7F7F7F7F;             // e8m0 scale = 1.0

    // V write addresses (one b32 per mt): state j = 32w+16mt+4q+r
    int wa[2];
    #pragma unroll
    for (int mt = 0; mt < 2; ++mt)
        wa[mt] = ((((2 * w + mt) >> 3) * 2 + mt) << 10)
               + ((w & 3) << 8) + (b << 4) + (q << 2);
    const int rbase = l << 4;

    // ---- persistent A-fragments (e4m3), both dirs: [dir][mt][c]
    v8i afrag[2][2][2];
    #pragma unroll
    for (int mt = 0; mt < 2; ++mt) {
        const int row = 32 * w + 16 * mt + b;
        #pragma unroll
        for (int c = 0; c < 2; ++c) {
            v8i aF, aB;
            #pragma unroll
            for (int g8 = 0; g8 < 8; ++g8) {
                floatx4 t = *(const floatx4*)(trans + row * N_ + c * 128 + q * 32 + 4 * g8);
                float eF[4], eB[4];
                #pragma unroll
                for (int ii = 0; ii < 4; ++ii) {
                    eF[ii] = __builtin_amdgcn_exp2f(t[ii] * LOG2E);
                    const int k = c * 128 + q * 32 + 4 * g8 + ii;
                    eB[ii] = __builtin_amdgcn_exp2f(trans[k * N_ + row] * LOG2E);
                }
                aF[g8] = pk_fp8x4(eF[0], eF[1], eF[2], eF[3]);
                aB[g8] = pk_fp8x4(eB[0], eB[1], eB[2], eB[3]);
            }
            afrag[0][mt][c] = aF;
            afrag[1][mt][c] = aB;
        }
    }

    // ---- mask-dead scan (once): any zero mask in this block's 16 columns?
    {
        const int* mrow = mask + blkLocal * GCOLS * T_;
        bool hd = false;
        #pragma unroll
        for (int i = 0; i < GCOLS * T_ / 512; ++i)
            hd |= (mrow[tid + 512 * i] == 0);
        if (tid == 0) sh.flag = 0;
        __syncthreads();
        if (__any(hd) && l == 0) atomicOr(&sh.flag, 1);
        __syncthreads();
    }
    const bool anyDead = (sh.flag != 0);

    const float* emitp = inputs + (size_t)bg * T_ * N_;
    const int*   maskp = mask + bg * T_;
    int   Ci[2] = {0, 0};
    float u[2][2][4];    // [dir][mt][r]

    // ---- init (s=0)
    #pragma unroll
    for (int mt = 0; mt < 2; ++mt) {       // fwd: exp(trans[:,START]+emit0)
        floatx4 em = *(const floatx4*)(emitp + j0 + 16 * mt);
        #pragma unroll
        for (int r = 0; r < 4; ++r) {
            const int j = j0 + 16 * mt + r;
            u[0][mt][r] = __builtin_amdgcn_exp2f((trans[j * N_ + START_] + em[r]) * LOG2E);
        }
    }
    #pragma unroll
    for (int mt = 0; mt < 2; ++mt) {       // bwd: exp(trans[STOP,:])
        floatx4 st = *(const floatx4*)(trans + STOP_ * N_ + j0 + 16 * mt);
        #pragma unroll
        for (int r = 0; r < 4; ++r)
            u[1][mt][r] = __builtin_amdgcn_exp2f(st[r] * LOG2E);
    }
    {   // init produce F
        float mx = u[0][0][0], sm = 0.f;
        #pragma unroll
        for (int mt = 0; mt < 2; ++mt)
            #pragma unroll
            for (int r = 0; r < 4; ++r) { mx = fmaxf(mx, u[0][mt][r]); sm += u[0][mt][r]; }
        mx = pmax16(mx); mx = pmax32(mx);
        if (l < 16)
            sh.mbufF[b * 8 + w] = (unsigned short)(__builtin_bit_cast(uint32_t, mx) >> 16);
        sm = psum32(sm);
        if (l < 32) sh.sbufF[b * 20 + w * 2 + q] = sm;
        #pragma unroll
        for (int mt = 0; mt < 2; ++mt)
            *(int*)(sh.VF[0] + wa[mt]) =
                pk_bf8x4(u[0][mt][0], u[0][mt][1], u[0][mt][2], u[0][mt][3]);
    }
    {   // init produce B: V_0 = u * exp(emit(511))
        float mx = u[1][0][0], sm = 0.f;
        #pragma unroll
        for (int mt = 0; mt < 2; ++mt)
            #pragma unroll
            for (int r = 0; r < 4; ++r) { mx = fmaxf(mx, u[1][mt][r]); sm += u[1][mt][r]; }
        mx = pmax16(mx); mx = pmax32(mx);
        if (l < 16)
            sh.mbufB[b * 8 + w] = (unsigned short)(__builtin_bit_cast(uint32_t, mx) >> 16);
        sm = psum32(sm);
        if (l < 32) sh.sbufB[b * 20 + w * 2 + q] = sm;
        #pragma unroll
        for (int mt = 0; mt < 2; ++mt) {
            floatx4 e = *(const floatx4*)(emitp + (size_t)511 * N_ + j0 + 16 * mt);
            float xp0 = __builtin_amdgcn_exp2f(e[0] * LOG2E);
            float xp1 = __builtin_amdgcn_exp2f(e[1] * LOG2E);
            float xp2 = __builtin_amdgcn_exp2f(e[2] * LOG2E);
            float xp3 = __builtin_amdgcn_exp2f(e[3] * LOG2E);
            *(int*)(sh.VB[0] + wa[mt]) =
                pk_bf8x4(u[1][mt][0] * xp0, u[1][mt][1] * xp1,
                         u[1][mt][2] * xp2, u[1][mt][3] * xp3);
        }
    }

    auto run = [&](auto fastc) {
        constexpr bool FAST = decltype(fastc)::value;

        // per-dir pipeline state (depth-2): xc = xp(s), ra = raw e(s+1)
        floatx4 xc[2][2], ra[2][2];
        const float* pe[2];
        const int*   pm[2] = {maskp, maskp};
        float mrot[2][2] = {{1.f, 1.f}, {1.f, 1.f}};

        {   // warm F: EIDX_F(s)=s
            const float* p = emitp + (size_t)1 * N_ + j0;
            floatx4 e0 = *(const floatx4*)p;
            floatx4 e1 = *(const floatx4*)(p + 16);
            ra[0][0] = *(const floatx4*)(p + N_);
            ra[0][1] = *(const floatx4*)(p + N_ + 16);
            pe[0] = p + 2 * N_;
            #pragma unroll
            for (int r = 0; r < 4; ++r) {
                xc[0][0][r] = __builtin_amdgcn_exp2f(e0[r] * LOG2E);
                xc[0][1][r] = __builtin_amdgcn_exp2f(e1[r] * LOG2E);
            }
        }
        {   // warm B: EIDX_B(s)=511-s
            const float* p = emitp + (size_t)510 * N_ + j0;
            floatx4 e0 = *(const floatx4*)p;
            floatx4 e1 = *(const floatx4*)(p + 16);
            ra[1][0] = *(const floatx4*)(p - N_);
            ra[1][1] = *(const floatx4*)(p - N_ + 16);
            pe[1] = p - 2 * N_;
            #pragma unroll
            for (int r = 0; r < 4; ++r) {
                xc[1][0][r] = __builtin_amdgcn_exp2f(e0[r] * LOG2E);
                xc[1][1][r] = __builtin_amdgcn_exp2f(e1[r] * LOG2E);
            }
        }
        if (!FAST) {
            mrot[0][0] = (float)maskp[0];    // MIDX_F(1)=0
            mrot[0][1] = (float)maskp[1];
            pm[0] = maskp + 2;               // MIDX_F(3)
            mrot[1][0] = (float)maskp[510];  // MIDX_B(1)=510
            mrot[1][1] = (float)maskp[509];
            pm[1] = maskp + 508;             // MIDX_B(3)
        }
        lds_barrier();

        auto step = [&](auto isfc, int pr, int cur) {
            constexpr bool ISF = decltype(isfc)::value;
            constexpr int  D = ISF ? 0 : 1;
            char (*V)[4096] = ISF ? sh.VF : sh.VB;
            unsigned short* mbufp = ISF ? sh.mbufF : sh.mbufB;
            const long estep = ISF ? (long)N_ : -(long)N_;

            // B fragments: 4 contiguous b128 (zero conflicts)
            const char* vb = V[pr];
            uintx4 r00 = *(const uintx4*)(vb + rbase);
            uintx4 r01 = *(const uintx4*)(vb + 1024 + rbase);
            uintx4 r10 = *(const uintx4*)(vb + 2048 + rbase);
            uintx4 r11 = *(const uintx4*)(vb + 3072 + rbase);
            // lag-1 max partials: ONE b128 = 8 u16 (bf16-trunc, positive)
            const uintx4 md = *(const uintx4*)((const uint32_t*)mbufp + b * 4);
            // prefetch raw emissions (distance-2)
            floatx4 eC0 = *(const floatx4*)pe[D];
            floatx4 eC1 = *(const floatx4*)(pe[D] + 16);
            float mC = 1.f;
            if (!FAST) mC = (float)(*pm[D]);

            // convert e(s+1) -> xp for next step (fills the LDS-wait shadow)
            floatx4 xn0, xn1;
            #pragma unroll
            for (int r = 0; r < 4; ++r) {
                xn0[r] = __builtin_amdgcn_exp2f(ra[D][0][r] * LOG2E);
                xn1[r] = __builtin_amdgcn_exp2f(ra[D][1][r] * LOG2E);
            }

            // integer max over 8 packed bf16 partials -> exponent -> rs
            const uint32_t hm = umax32(umax32(md[0], md[1]), umax32(md[2], md[3]));
            const uint32_t lm = umax32(umax32(md[0] << 16, md[1] << 16),
                                       umax32(md[2] << 16, md[3] << 16));
            const uint32_t mm = umax32(hm, lm);
            const int eb = (int)((mm >> 23) & 0xFFu);
            const float rs = __builtin_bit_cast(float, (uint32_t)(249 - eb) << 23);
            Ci[D] += eb;

            floatx4 rx0, rx1;       // fwd: fold rs into xp off the MFMA tail
            if (ISF) {
                #pragma unroll
                for (int r = 0; r < 4; ++r) {
                    rx0[r] = xc[0][0][r] * rs;
                    rx1[r] = xc[0][1][r] * rs;
                }
            }

            union { v8i v; struct { uintx4 lo, hi; } p; } bf0, bf1;
            bf0.p.lo = r00; bf0.p.hi = r01;
            bf1.p.lo = r10; bf1.p.hi = r11;

            floatx4 a0 = {0.f,0.f,0.f,0.f}, a1 = {0.f,0.f,0.f,0.f};
            a0 = __builtin_amdgcn_mfma_scale_f32_16x16x128_f8f6f4(
                     afrag[D][0][0], bf0.v, a0, 0, 1, 0, scl, 0, scl);
            a1 = __builtin_amdgcn_mfma_scale_f32_16x16x128_f8f6f4(
                     afrag[D][1][0], bf0.v, a1, 0, 1, 0, scl, 0, scl);
            a0 = __builtin_amdgcn_mfma_scale_f32_16x16x128_f8f6f4(
                     afrag[D][0][1], bf1.v, a0, 0, 1, 0, scl, 0, scl);
            a1 = __builtin_amdgcn_mfma_scale_f32_16x16x128_f8f6f4(
                     afrag[D][1][1], bf1.v, a1, 0, 1, 0, scl, 0, scl);

            if (FAST) {
                #pragma unroll
                for (int r = 0; r < 4; ++r) {
                    if (ISF) {
                        u[0][0][r] = a0[r] * rx0[r];
                        u[0][1][r] = a1[r] * rx1[r];
                    } else {
                        u[1][0][r] = a0[r] * rs;
                        u[1][1][r] = a1[r] * rs;
                    }
                }
            } else {
                const bool live = (mrot[D][cur] != 0.f);
                float csv = 0.f;
                if (__any(!live)) {
                    const float* sb = (ISF ? sh.sbufF : sh.sbufB) + b * 20;
                    floatx4 s0 = *(const floatx4*)sb,       s1 = *(const floatx4*)(sb + 4);
                    floatx4 s2 = *(const floatx4*)(sb + 8), s3 = *(const floatx4*)(sb + 12);
                    csv = ((((s0[0] + s0[1]) + (s0[2] + s0[3])) +
                            ((s1[0] + s1[1]) + (s1[2] + s1[3]))) +
                           (((s2[0] + s2[1]) + (s2[2] + s2[3])) +
                            ((s3[0] + s3[1]) + (s3[2] + s3[3])))) * rs;
                }
                #pragma unroll
                for (int r = 0; r < 4; ++r) {
                    if (ISF) {
                        u[0][0][r] = live ? a0[r] * rx0[r] : csv;
                        u[0][1][r] = live ? a1[r] * rx1[r] : csv;
                    } else {
                        u[1][0][r] = live ? a0[r] * rs : csv;
                        u[1][1][r] = live ? a1[r] * rs : csv;
                    }
                }
            }

            // produce: per-lane max tree -> VALU butterfly -> u16 partial
            {
                float t0 = fmax3(u[D][0][0], u[D][0][1], u[D][0][2]);
                t0 = fmax3(t0, u[D][0][3], u[D][1][0]);
                t0 = fmax3(t0, u[D][1][1], u[D][1][2]);
                t0 = fmaxf(t0, u[D][1][3]);
                t0 = pmax16(t0);
                t0 = pmax32(t0);
                if (l < 16)
                    mbufp[b * 8 + w] =
                        (unsigned short)(__builtin_bit_cast(uint32_t, t0) >> 16);
                if (!FAST) {
                    float sm = ((u[D][0][0] + u[D][0][1]) + (u[D][0][2] + u[D][0][3]))
                             + ((u[D][1][0] + u[D][1][1]) + (u[D][1][2] + u[D][1][3]));
                    sm = psum32(sm);
                    if (l < 32) (ISF ? sh.sbufF : sh.sbufB)[b * 20 + w * 2 + q] = sm;
                }
            }
            // write V: fwd V=u ; bwd V=u*xp
            if (ISF) {
                *(int*)(V[pr ^ 1] + wa[0]) =
                    pk_bf8x4(u[0][0][0], u[0][0][1], u[0][0][2], u[0][0][3]);
                *(int*)(V[pr ^ 1] + wa[1]) =
                    pk_bf8x4(u[0][1][0], u[0][1][1], u[0][1][2], u[0][1][3]);
            } else {
                *(int*)(V[pr ^ 1] + wa[0]) =
                    pk_bf8x4(u[1][0][0] * xc[1][0][0], u[1][0][1] * xc[1][0][1],
                             u[1][0][2] * xc[1][0][2], u[1][0][3] * xc[1][0][3]);
                *(int*)(V[pr ^ 1] + wa[1]) =
                    pk_bf8x4(u[1][1][0] * xc[1][1][0], u[1][1][1] * xc[1][1][1],
                             u[1][1][2] * xc[1][1][2], u[1][1][3] * xc[1][1][3]);
            }
            // rotate pipeline (registers only; barrier handled by caller)
            xc[D][0] = xn0; xc[D][1] = xn1;
            ra[D][0] = eC0; ra[D][1] = eC1;
            pe[D] += estep;
            if (!FAST) { mrot[D][cur] = mC; pm[D] += ISF ? 1 : -1; }
        };

        #pragma unroll 1
        for (int g = 0; g < 127; ++g) {
            step(BC<true>{}, 0, 0);   // F step
            step(BC<false>{}, 0, 0);  // B step
            lds_barrier();
            step(BC<true>{}, 1, 1);
            step(BC<false>{}, 1, 1);
            lds_barrier();
        }
        step(BC<true>{}, 0, 0);       // F step 255
        step(BC<false>{}, 0, 0);      // B step 255 (done: 255)
        lds_barrier();
        step(BC<true>{}, 1, 1);       // F step 256 (no barrier needed after)
    };

    if (anyDead) run(BC<false>{});
    else         run(BC<true>{});

    // ---- store partials: alpha(256) / beta(256), scale 2^-C
    #pragma unroll
    for (int mt = 0; mt < 2; ++mt) {
        floatx4 vf = {u[0][mt][0], u[0][mt][1], u[0][mt][2], u[0][mt][3]};
        *(floatx4*)&ws[(size_t)bg * N_ + j0 + 16 * mt] = vf;
        floatx4 vbb = {u[1][mt][0], u[1][mt][1], u[1][mt][2], u[1][mt][3]};
        *(floatx4*)&ws[WSB_OFF + (size_t)bg * N_ + j0 + 16 * mt] = vbb;
    }
    if (tid < 16) {
        ws[WCF_OFF + blkLocal * GCOLS + tid] = (float)(Ci[0] - 122 * 256);
        ws[WCB_OFF + blkLocal * GCOLS + tid] = (float)(Ci[1] - 122 * 255);
    }
}

__global__ __launch_bounds__(512, 2) void crf_main(
    const float* __restrict__ inputs, const float* __restrict__ trans,
    const int* __restrict__ tags, const int* __restrict__ mask,
    float* __restrict__ out, float* __restrict__ ws)
{
    __shared__ DenomShared sh;

    if (blockIdx.x >= NDM) {
        // ---------------- numerator: one batch per block ----------------
        float* nred = sh.sbufF;              // [0,8)
        int*   nredi = (int*)(sh.sbufF + 8); // [8,16)
        const int bb = blockIdx.x - NDM;
        const int t  = threadIdx.x;            // 0..511
        const int tg = tags[bb * T_ + t];
        const float fm = (float)mask[bb * T_ + t];
        float part = 0.f;
        if (t >= 1)      part += trans[tg * N_ + tags[bb * T_ + t - 1]] * fm;
        if (t <= T_ - 2) part += inputs[((size_t)bb * T_ + t) * N_ + tg] * fm;
        int ms = mask[bb * T_ + t];
        #pragma unroll
        for (int off = 1; off < 64; off <<= 1) {
            part += __shfl_xor(part, off, 64);
            ms   += __shfl_xor(ms, off, 64);
        }
        if ((t & 63) == 0) { nred[t >> 6] = part; nredi[t >> 6] = ms; }
        __syncthreads();
        if (t == 0) {
            float tot = 0.f; int mtot = 0;
            for (int i = 0; i < 8; ++i) { tot += nred[i]; mtot += nredi[i]; }
            tot += trans[tags[bb * T_] * N_ + START_];
            const int last = mtot - 1;
            const int lt = tags[bb * T_ + last];
            tot += trans[STOP_ * N_ + lt]
                 + inputs[((size_t)bb * T_ + (T_ - 1)) * N_ + lt]
                   * (float)mask[bb * T_ + T_ - 1];
            ws[WNUM_OFF + bb] = tot;       // combine sums it (no contended atomic)
        }
        return;
    }

    denom_both(sh, inputs, trans, mask, ws, blockIdx.x);
}

// out += sum_b (num_b - denom_b); denom_b = LN2*(CF+CB+log2(sum_j alphaF*betaB))
// 16 blocks x 16 batches, ONE atomicAdd per block.
__global__ __launch_bounds__(256) void crf_combine(
    const float* __restrict__ ws, float* __restrict__ out)
{
    __shared__ float red[4];
    const int t = threadIdx.x;
    const int w = t >> 6, l = t & 63;
    float acc = 0.f;
    #pragma unroll 1
    for (int i = 0; i < 4; ++i) {
        const int bb = blockIdx.x * GCOLS + w * 4 + i;
        const float* pa = ws + (size_t)bb * N_;
        const float* pb = ws + WSB_OFF + (size_t)bb * N_;
        floatx4 va = *(const floatx4*)(pa + 4 * l);
        floatx4 vb = *(const floatx4*)(pb + 4 * l);
        float p = va[0] * vb[0] + va[1] * vb[1] + va[2] * vb[2] + va[3] * vb[3];
        #pragma unroll
        for (int off = 1; off < 64; off <<= 1) p += __shfl_xor(p, off, 64);
        if (l == 0) {
            const float denom = (ws[WCF_OFF + bb] + ws[WCB_OFF + bb]
                                 + __builtin_amdgcn_logf(p)) * LN2;
            acc += ws[WNUM_OFF + bb] - denom;
        }
    }
    if (l == 0) red[w] = acc;
    __syncthreads();
    if (t == 0) atomicAdd(out, red[0] + red[1] + red[2] + red[3]);
}

extern "C" void kernel_launch(void* const* d_in, const int* in_sizes, int n_in,
                              void* d_out, int out_size, void* d_ws, size_t ws_size,
                              hipStream_t stream) {
    const float* inputs = (const float*)d_in[0];
    const float* trans  = (const float*)d_in[1];
    const int*   tags   = (const int*)d_in[2];
    const int*   mask   = (const int*)d_in[3];
    float* out = (float*)d_out;
    float* ws  = (float*)d_ws;
    hipMemsetAsync(out, 0, sizeof(float), stream);
    crf_main<<<dim3(NDM + B_), dim3(512), 0, stream>>>(inputs, trans, tags, mask, out, ws);
    crf_combine<<<dim3(B_ / GCOLS), dim3(256), 0, stream>>>(ws, out);
}

// Round 7
// 330.829 us; speedup vs baseline: 1.3588x; 1.3588x over previous
//
#include <hip/hip_runtime.h>
#include <hip/hip_bf16.h>
#include <stdint.h>

#define B_    256
#define T_    512
#define N_    256
#define START_ 254
#define STOP_  255
#define GCOLS 16
#define NF    16          // forward denominator blocks
#define ND    32          // total denominator blocks (16 fwd + 16 bwd)
#define LOG2E 1.4426950408889634f
#define LN2   0.6931471805599453f

// d_ws float layout: [0,65536) alphaF, [65536,131072) betaB, [131072,131328) CF,
// [131328,131584) CB, [131584,131840) numerator partials
#define WSB_OFF 65536
#define WCF_OFF 131072
#define WCB_OFF 131328
#define WNUM_OFF 131584

typedef __attribute__((ext_vector_type(4))) float floatx4;
typedef __attribute__((ext_vector_type(4))) unsigned int uintx4;
typedef __attribute__((ext_vector_type(8))) int v8i;

template<bool X> struct BC { static constexpr bool value = X; };

__device__ __forceinline__ void lds_barrier() {
    asm volatile("s_waitcnt lgkmcnt(0)\n\ts_barrier" ::: "memory");
}
__device__ __forceinline__ float fmax3(float a, float b, float c) {
    return fmaxf(fmaxf(a, b), c);   // clang fuses to v_max3_f32
}
__device__ __forceinline__ uint32_t umax32(uint32_t a, uint32_t b) {
    return a > b ? a : b;           // v_max_u32
}
// VALU-pipe butterfly (keeps reduce off the DS unit): after swap,
// {a, b} = {x[l], x[l^16]} (resp ^32).
__device__ __forceinline__ float pmax16(float x) {
    float a = x, b = x;
    asm("v_permlane16_swap_b32 %0, %1" : "+v"(a), "+v"(b));
    return fmaxf(a, b);
}
__device__ __forceinline__ float pmax32(float x) {
    float a = x, b = x;
    asm("v_permlane32_swap_b32 %0, %1" : "+v"(a), "+v"(b));
    return fmaxf(a, b);
}
__device__ __forceinline__ float psum32(float x) {
    float a = x, b = x;
    asm("v_permlane32_swap_b32 %0, %1" : "+v"(a), "+v"(b));
    return a + b;
}

__device__ __forceinline__ int pk_fp8x4(float a, float b, float c, float d) {  // e4m3
    int r = __builtin_amdgcn_cvt_pk_fp8_f32(a, b, 0, false);
    return __builtin_amdgcn_cvt_pk_fp8_f32(c, d, r, true);
}
__device__ __forceinline__ int pk_bf8x4(float a, float b, float c, float d) {  // e5m2
    int r = __builtin_amdgcn_cvt_pk_bf8_f32(a, b, 0, false);
    return __builtin_amdgcn_cvt_pk_bf8_f32(c, d, r, true);
}

// V layout (per buffer, 4096 B): element (k, col b), k = state index:
//   c=k>>7, qk=(k>>5)&3, j=k&31, r=j>>4, j'=j&15
//   addr = ((c*2+r)<<10) + (qk<<8) + (b<<4) + j'
// Read (lane l=q*16+b, chunk c): two b128 at (2c)*1024+16l and (2c+1)*1024+16l
// -> contiguous 1KB per wave per page, zero conflicts.
// mbuf: per-column max partials packed as truncated-bf16 u16[8] (one 16B row
// per column -> consumer is ONE ds_read_b128). Positive floats compare
// correctly as integers; truncation never changes the exponent, and rs/eb use
// only the exponent -> bit-identical to the f32 path.
// NOTE: lag-1 normalization only. Lag-2 (R5) is dynamically UNSTABLE:
// m_s = m_{s-1} - m_{s-2} + c_s has unit-circle roots (period-6 resonance),
// noise-driven amplitude ~ sigma*sqrt(s) overflows e5m2 -> NaN.
struct DenomShared {
    alignas(16) char  V[2][4096];
    alignas(16) unsigned short mbuf[GCOLS * 8];  // [b][w] bf16-trunc max partials
    alignas(16) float sbuf[GCOLS * 20];          // sum partials (mask-dead path only)
    int flag;
};

// 512 threads = 8 waves; wave w owns rows [32w,32w+32) as 2 M-tiles.
// Lane l: q=l>>4, b=l&15 (batch column). A = E (e4m3, fwd) / E^T (bwd),
// persistent in VGPRs. B = V (e5m2) in LDS, dbuffered.
// Emission pipeline: load raw @ distance-3, convert xp=exp2(e*LOG2E) @
// distance-1, consume @ distance-0. Rescale rs is a pure power of two.
// Tail order: V pack+write FIRST (so the pre-barrier lgkmcnt(0) drain starts
// ~26cy earlier), then the max-tree produce runs under the drain.
template<bool ISF>
__device__ __forceinline__ void denom_path(
    DenomShared& sh, const float* __restrict__ inputs,
    const float* __restrict__ trans, const int* __restrict__ mask,
    float* __restrict__ ws, int blkLocal)
{
    const int tid = threadIdx.x;
    const int w = tid >> 6;
    const int l = tid & 63;
    const int q = l >> 4;
    const int b = l & 15;
    const int bg = blkLocal * GCOLS + b;
    const int j0 = 32 * w + 4 * q;          // + 16*mt
    const int S = ISF ? 256 : 255;          // serial steps after init
    const int scl = 0x7F7F7F7F;             // e8m0 scale = 1.0

    auto EIDX = [](int s) { return ISF ? s : (511 - s); };
    auto MIDX = [](int s) { return ISF ? (s - 1) : (511 - s); };

    // V write addresses (one b32 per mt): state j = 32w+16mt+4q+r
    int wa[2];
    #pragma unroll
    for (int mt = 0; mt < 2; ++mt)
        wa[mt] = ((((2 * w + mt) >> 3) * 2 + mt) << 10)
               + ((w & 3) << 8) + (b << 4) + (q << 2);
    const int rbase = l << 4;

    // ---- persistent A-fragments (e4m3): lane holds E[row][c*128+q*32 .. +32)
    v8i afrag[2][2];
    #pragma unroll
    for (int mt = 0; mt < 2; ++mt) {
        const int row = 32 * w + 16 * mt + b;
        #pragma unroll
        for (int c = 0; c < 2; ++c) {
            v8i a;
            #pragma unroll
            for (int g8 = 0; g8 < 8; ++g8) {
                float e[4];
                if (ISF) {
                    floatx4 t = *(const floatx4*)(trans + row * N_ + c * 128 + q * 32 + 4 * g8);
                    #pragma unroll
                    for (int ii = 0; ii < 4; ++ii)
                        e[ii] = __builtin_amdgcn_exp2f(t[ii] * LOG2E);
                } else {
                    #pragma unroll
                    for (int ii = 0; ii < 4; ++ii) {
                        const int k = c * 128 + q * 32 + 4 * g8 + ii;
                        e[ii] = __builtin_amdgcn_exp2f(trans[k * N_ + row] * LOG2E);
                    }
                }
                a[g8] = pk_fp8x4(e[0], e[1], e[2], e[3]);
            }
            afrag[mt][c] = a;
        }
    }

    // ---- mask-dead scan (once): any zero mask in this block's 16 columns?
    {
        const int* mrow = mask + blkLocal * GCOLS * T_;
        bool hd = false;
        #pragma unroll
        for (int i = 0; i < GCOLS * T_ / 512; ++i)
            hd |= (mrow[tid + 512 * i] == 0);
        if (tid == 0) sh.flag = 0;
        __syncthreads();
        if (__any(hd) && l == 0) atomicOr(&sh.flag, 1);
        __syncthreads();
    }
    const bool anyDead = (sh.flag != 0);

    const float* emitp = inputs + (size_t)bg * T_ * N_;
    const int*   maskp = mask + bg * T_;
    int   Ci = 0;
    float u[2][4];

    // ---- init (s=0): fwd u=exp(trans[:,START]+emit0); bwd u=exp(trans[STOP,:])
    if (ISF) {
        #pragma unroll
        for (int mt = 0; mt < 2; ++mt) {
            floatx4 em = *(const floatx4*)(emitp + j0 + 16 * mt);
            #pragma unroll
            for (int r = 0; r < 4; ++r) {
                const int j = j0 + 16 * mt + r;
                u[mt][r] = __builtin_amdgcn_exp2f((trans[j * N_ + START_] + em[r]) * LOG2E);
            }
        }
    } else {
        #pragma unroll
        for (int mt = 0; mt < 2; ++mt) {
            floatx4 st = *(const floatx4*)(trans + STOP_ * N_ + j0 + 16 * mt);
            #pragma unroll
            for (int r = 0; r < 4; ++r)
                u[mt][r] = __builtin_amdgcn_exp2f(st[r] * LOG2E);
        }
    }
    {   // init produce (both formats) + V0 write
        float mx = u[0][0], sm = 0.f;
        #pragma unroll
        for (int mt = 0; mt < 2; ++mt)
            #pragma unroll
            for (int r = 0; r < 4; ++r) { mx = fmaxf(mx, u[mt][r]); sm += u[mt][r]; }
        mx = pmax16(mx);
        mx = pmax32(mx);
        if (l < 16)
            sh.mbuf[b * 8 + w] =
                (unsigned short)(__builtin_bit_cast(uint32_t, mx) >> 16);
        sm = psum32(sm);
        if (l < 32) sh.sbuf[b * 20 + w * 2 + q] = sm;

        float xpi[2][4] = {{1.f,1.f,1.f,1.f},{1.f,1.f,1.f,1.f}};
        if (!ISF) {   // bwd V_0 = u * exp(emit(511))
            #pragma unroll
            for (int mt = 0; mt < 2; ++mt) {
                floatx4 e = *(const floatx4*)(emitp + (size_t)511 * N_ + j0 + 16 * mt);
                #pragma unroll
                for (int r = 0; r < 4; ++r)
                    xpi[mt][r] = __builtin_amdgcn_exp2f(e[r] * LOG2E);
            }
        }
        #pragma unroll
        for (int mt = 0; mt < 2; ++mt)
            *(int*)(sh.V[0] + wa[mt]) =
                pk_bf8x4(u[mt][0] * xpi[mt][0], u[mt][1] * xpi[mt][1],
                         u[mt][2] * xpi[mt][2], u[mt][3] * xpi[mt][3]);
    }

    auto run = [&](auto fastc) {
        constexpr bool FAST = decltype(fastc)::value;
        const long estep = ISF ? (long)N_ : -(long)N_;
        const int  mstep = ISF ? 1 : -1;

        // emission pipeline registers
        floatx4 xc0, xc1;          // xp for the current body
        floatx4 rbA0, rbA1;        // raw e(s+1)  (converted this body)
        floatx4 rbB0, rbB1;        // raw e(s+2)  (in flight / arrived)
        const float* pe = emitp + (size_t)EIDX(1) * N_ + j0;
        {
            floatx4 e0 = *(const floatx4*)pe;
            floatx4 e1 = *(const floatx4*)(pe + 16);
            pe += estep;
            rbA0 = *(const floatx4*)pe;
            rbA1 = *(const floatx4*)(pe + 16);
            pe += estep;
            rbB0 = *(const floatx4*)pe;
            rbB1 = *(const floatx4*)(pe + 16);
            pe += estep;            // now at EIDX(4) = body 1's load target
            #pragma unroll
            for (int r = 0; r < 4; ++r) {
                xc0[r] = __builtin_amdgcn_exp2f(e0[r] * LOG2E);
                xc1[r] = __builtin_amdgcn_exp2f(e1[r] * LOG2E);
            }
        }
        float mrot[2] = {1.f, 1.f};
        const int* pm = maskp;
        if (!FAST) {
            mrot[0] = (float)maskp[MIDX(1)];
            mrot[1] = (float)maskp[MIDX(2)];
            pm = maskp + MIDX(3);
        }
        lds_barrier();

        auto body = [&](int pr, int cur) {
            // B fragments first: 4 contiguous b128 (zero conflicts)
            const char* vb = sh.V[pr];
            uintx4 r00 = *(const uintx4*)(vb + rbase);
            uintx4 r01 = *(const uintx4*)(vb + 1024 + rbase);
            uintx4 r10 = *(const uintx4*)(vb + 2048 + rbase);
            uintx4 r11 = *(const uintx4*)(vb + 3072 + rbase);
            // lag-1 max partials: ONE b128 = 8 u16 (bf16-trunc, positive)
            const uintx4 md = *(const uintx4*)((const uint32_t*)sh.mbuf + b * 4);
            // prefetch raw emissions (distance-3)
            floatx4 eC0 = *(const floatx4*)pe;
            floatx4 eC1 = *(const floatx4*)(pe + 16);
            float mC = 1.f;
            if (!FAST) mC = (float)(*pm);

            // convert e(s+1) -> xp for next body (fills the LDS-wait shadow)
            floatx4 xn0, xn1;
            #pragma unroll
            for (int r = 0; r < 4; ++r) {
                xn0[r] = __builtin_amdgcn_exp2f(rbA0[r] * LOG2E);
                xn1[r] = __builtin_amdgcn_exp2f(rbA1[r] * LOG2E);
            }

            // integer max over 8 packed bf16 partials -> exponent -> rs
            const uint32_t hm = umax32(umax32(md[0], md[1]), umax32(md[2], md[3]));
            const uint32_t lm = umax32(umax32(md[0] << 16, md[1] << 16),
                                       umax32(md[2] << 16, md[3] << 16));
            const uint32_t mm = umax32(hm, lm);
            const int eb = (int)((mm >> 23) & 0xFFu);
            const float rs = __builtin_bit_cast(float, (uint32_t)(249 - eb) << 23);
            Ci += eb;

            floatx4 rx0, rx1;       // fwd: fold rs into xp off the MFMA tail
            if (ISF) {
                #pragma unroll
                for (int r = 0; r < 4; ++r) { rx0[r] = xc0[r] * rs; rx1[r] = xc1[r] * rs; }
            }

            union { v8i v; struct { uintx4 lo, hi; } p; } bf0, bf1;
            bf0.p.lo = r00; bf0.p.hi = r01;
            bf1.p.lo = r10; bf1.p.hi = r11;

            floatx4 a0 = {0.f,0.f,0.f,0.f}, a1 = {0.f,0.f,0.f,0.f};
            a0 = __builtin_amdgcn_mfma_scale_f32_16x16x128_f8f6f4(
                     afrag[0][0], bf0.v, a0, 0, 1, 0, scl, 0, scl);
            a1 = __builtin_amdgcn_mfma_scale_f32_16x16x128_f8f6f4(
                     afrag[1][0], bf0.v, a1, 0, 1, 0, scl, 0, scl);
            a0 = __builtin_amdgcn_mfma_scale_f32_16x16x128_f8f6f4(
                     afrag[0][1], bf1.v, a0, 0, 1, 0, scl, 0, scl);
            a1 = __builtin_amdgcn_mfma_scale_f32_16x16x128_f8f6f4(
                     afrag[1][1], bf1.v, a1, 0, 1, 0, scl, 0, scl);

            if (FAST) {
                #pragma unroll
                for (int r = 0; r < 4; ++r) {
                    if (ISF) {
                        u[0][r] = a0[r] * rx0[r];
                        u[1][r] = a1[r] * rx1[r];
                    } else {
                        u[0][r] = a0[r] * rs;
                        u[1][r] = a1[r] * rs;
                    }
                }
            } else {
                const bool live = (mrot[cur] != 0.f);
                float csv = 0.f;
                if (__any(!live)) {
                    const float* sb = &sh.sbuf[b * 20];
                    floatx4 s0 = *(const floatx4*)sb,       s1 = *(const floatx4*)(sb + 4);
                    floatx4 s2 = *(const floatx4*)(sb + 8), s3 = *(const floatx4*)(sb + 12);
                    csv = ((((s0[0] + s0[1]) + (s0[2] + s0[3])) +
                            ((s1[0] + s1[1]) + (s1[2] + s1[3]))) +
                           (((s2[0] + s2[1]) + (s2[2] + s2[3])) +
                            ((s3[0] + s3[1]) + (s3[2] + s3[3])))) * rs;
                }
                #pragma unroll
                for (int r = 0; r < 4; ++r) {
                    if (ISF) {
                        u[0][r] = live ? a0[r] * rx0[r] : csv;
                        u[1][r] = live ? a1[r] * rx1[r] : csv;
                    } else {
                        u[0][r] = live ? a0[r] * rs : csv;
                        u[1][r] = live ? a1[r] * rs : csv;
                    }
                }
            }

            // write V FIRST (drain starts early): fwd V=u ; bwd V=u*xp
            if (ISF) {
                *(int*)(sh.V[pr ^ 1] + wa[0]) = pk_bf8x4(u[0][0], u[0][1], u[0][2], u[0][3]);
                *(int*)(sh.V[pr ^ 1] + wa[1]) = pk_bf8x4(u[1][0], u[1][1], u[1][2], u[1][3]);
            } else {
                *(int*)(sh.V[pr ^ 1] + wa[0]) =
                    pk_bf8x4(u[0][0] * xc0[0], u[0][1] * xc0[1],
                             u[0][2] * xc0[2], u[0][3] * xc0[3]);
                *(int*)(sh.V[pr ^ 1] + wa[1]) =
                    pk_bf8x4(u[1][0] * xc1[0], u[1][1] * xc1[1],
                             u[1][2] * xc1[2], u[1][3] * xc1[3]);
            }
            // produce (runs under the LDS-write drain): max tree -> u16 partial
            {
                float t0 = fmax3(u[0][0], u[0][1], u[0][2]);
                t0 = fmax3(t0, u[0][3], u[1][0]);
                t0 = fmax3(t0, u[1][1], u[1][2]);
                t0 = fmaxf(t0, u[1][3]);
                t0 = pmax16(t0);
                t0 = pmax32(t0);
                if (l < 16)
                    sh.mbuf[b * 8 + w] =
                        (unsigned short)(__builtin_bit_cast(uint32_t, t0) >> 16);
                if (!FAST) {
                    float sm = ((u[0][0] + u[0][1]) + (u[0][2] + u[0][3]))
                             + ((u[1][0] + u[1][1]) + (u[1][2] + u[1][3]));
                    sm = psum32(sm);
                    if (l < 32) sh.sbuf[b * 20 + w * 2 + q] = sm;
                }
            }
            lds_barrier();
            // rotate pipeline
            xc0 = xn0; xc1 = xn1;
            rbA0 = rbB0; rbA1 = rbB1;
            rbB0 = eC0;  rbB1 = eC1;
            pe += estep;
            if (!FAST) { mrot[cur] = mC; pm += mstep; }
        };

        #pragma unroll 1
        for (int g = 0; g < S / 2; ++g) {
            body(0, 0);
            body(1, 1);
        }
        if (S & 1) body(0, 0);
    };

    if (anyDead) run(BC<false>{});
    else         run(BC<true>{});

    // ---- store partials: u = alpha(256) (fwd) / beta(256) (bwd), scale 2^-C
    float* wsV = ws + (ISF ? 0 : WSB_OFF);
    #pragma unroll
    for (int mt = 0; mt < 2; ++mt) {
        floatx4 vv = {u[mt][0], u[mt][1], u[mt][2], u[mt][3]};
        *(floatx4*)&wsV[(size_t)bg * N_ + j0 + 16 * mt] = vv;
    }
    if (tid < 16) {
        float* wsC = ws + (ISF ? WCF_OFF : WCB_OFF);
        wsC[blkLocal * GCOLS + tid] = (float)(Ci - 122 * S);
    }
}

__global__ __launch_bounds__(512, 2) void crf_main(
    const float* __restrict__ inputs, const float* __restrict__ trans,
    const int* __restrict__ tags, const int* __restrict__ mask,
    float* __restrict__ out, float* __restrict__ ws)
{
    __shared__ DenomShared sh;

    if (blockIdx.x >= ND) {
        // ---------------- numerator: one batch per block ----------------
        float* nred = sh.sbuf;              // [0,8)
        int*   nredi = (int*)(sh.sbuf + 8); // [8,16)
        const int bb = blockIdx.x - ND;
        const int t  = threadIdx.x;            // 0..511
        const int tg = tags[bb * T_ + t];
        const float fm = (float)mask[bb * T_ + t];
        float part = 0.f;
        if (t >= 1)      part += trans[tg * N_ + tags[bb * T_ + t - 1]] * fm;
        if (t <= T_ - 2) part += inputs[((size_t)bb * T_ + t) * N_ + tg] * fm;
        int ms = mask[bb * T_ + t];
        #pragma unroll
        for (int off = 1; off < 64; off <<= 1) {
            part += __shfl_xor(part, off, 64);
            ms   += __shfl_xor(ms, off, 64);
        }
        if ((t & 63) == 0) { nred[t >> 6] = part; nredi[t >> 6] = ms; }
        __syncthreads();
        if (t == 0) {
            float tot = 0.f; int mtot = 0;
            for (int i = 0; i < 8; ++i) { tot += nred[i]; mtot += nredi[i]; }
            tot += trans[tags[bb * T_] * N_ + START_];
            const int last = mtot - 1;
            const int lt = tags[bb * T_ + last];
            tot += trans[STOP_ * N_ + lt]
                 + inputs[((size_t)bb * T_ + (T_ - 1)) * N_ + lt]
                   * (float)mask[bb * T_ + T_ - 1];
            ws[WNUM_OFF + bb] = tot;       // combine sums it (no contended atomic)
        }
        return;
    }

    if (blockIdx.x < NF) denom_path<true>(sh, inputs, trans, mask, ws, blockIdx.x);
    else                 denom_path<false>(sh, inputs, trans, mask, ws, blockIdx.x - NF);
}

// out += sum_b (num_b - denom_b); denom_b = LN2*(CF+CB+log2(sum_j alphaF*betaB))
// 16 blocks x 16 batches, ONE atomicAdd per block.
__global__ __launch_bounds__(256) void crf_combine(
    const float* __restrict__ ws, float* __restrict__ out)
{
    __shared__ float red[4];
    const int t = threadIdx.x;
    const int w = t >> 6, l = t & 63;
    float acc = 0.f;
    #pragma unroll 1
    for (int i = 0; i < 4; ++i) {
        const int bb = blockIdx.x * GCOLS + w * 4 + i;
        const float* pa = ws + (size_t)bb * N_;
        const float* pb = ws + WSB_OFF + (size_t)bb * N_;
        floatx4 va = *(const floatx4*)(pa + 4 * l);
        floatx4 vb = *(const floatx4*)(pb + 4 * l);
        float p = va[0] * vb[0] + va[1] * vb[1] + va[2] * vb[2] + va[3] * vb[3];
        #pragma unroll
        for (int off = 1; off < 64; off <<= 1) p += __shfl_xor(p, off, 64);
        if (l == 0) {
            const float denom = (ws[WCF_OFF + bb] + ws[WCB_OFF + bb]
                                 + __builtin_amdgcn_logf(p)) * LN2;
            acc += ws[WNUM_OFF + bb] - denom;
        }
    }
    if (l == 0) red[w] = acc;
    __syncthreads();
    if (t == 0) atomicAdd(out, red[0] + red[1] + red[2] + red[3]);
}

extern "C" void kernel_launch(void* const* d_in, const int* in_sizes, int n_in,
                              void* d_out, int out_size, void* d_ws, size_t ws_size,
                              hipStream_t stream) {
    const float* inputs = (const float*)d_in[0];
    const float* trans  = (const float*)d_in[1];
    const int*   tags   = (const int*)d_in[2];
    const int*   mask   = (const int*)d_in[3];
    float* out = (float*)d_out;
    float* ws  = (float*)d_ws;
    hipMemsetAsync(out, 0, sizeof(float), stream);
    crf_main<<<dim3(ND + B_), dim3(512), 0, stream>>>(inputs, trans, tags, mask, out, ws);
    crf_combine<<<dim3(B_ / GCOLS), dim3(256), 0, stream>>>(ws, out);
}